// Round 14
// baseline (1924.449 us; speedup 1.0000x reference)
//
#include <hip/hip_runtime.h>
#include <stdint.h>

// Echo-state network (fp32 in, fp32 out). Round 28: 32x32x16 MFMA retile on
// the R23 skeleton (1511 us). R27 post-mortem: XCD-affinity refuted (1549);
// R23 budget says ds_read_b128 port = 57% of phase time, set by the 16x16
// fragment shape (every wave reads ALL of B, x4). v_mfma_f32_32x32x16_f16
// reads the same 16B/lane/operand but makes 4x outputs: block = 128 thr
// (2 waves), tile 64x32, wave = 32x32 (acc = floatx16 x2, 3 MFMAs/quarter,
// 4 K-quarters/chunk). Block-chunk reads 32 b128 (was 48) for the same
// output -> port 1728 -> 1152 cy/phase. Everything else verbatim R23:
// 768 grid + R18 swizzle (balance!), GLOAD16 2-deep dbuf (same 24 DMAs/
// chunk/block, same XOR swizzle: LDS[r][g] = G[r][g^(r&7)], read granule
// ((2q+hi)^(lane&7))), 1 __syncthreads/chunk, 17 chunks, 48 KB LDS ->
// 3 blocks/CU (6 waves/CU - the risk; R24's 4 waves/CU was fatal).
// C/D map (guide, m74-family): col=lane&31, row=(reg&3)+8*(reg>>2)+
// 4*(lane>>5). Head: 5-step 32-lane tree, same g = b*32+it groups ->
// head_reduce unchanged. K accumulates in 16-granules (not bit-identical
// to R23; delta ~1e-6 << 0.0156 f16 floor).

typedef _Float16 f16;
typedef _Float16 f16x8 __attribute__((ext_vector_type(8)));
typedef float floatx16 __attribute__((ext_vector_type(16)));

#define N_TOT 256
#define T_TOT 70
#define V_TOT 64
#define B_TOT 6
#define H_TOT 1024
#define C_TOT 4
#define F_TOT (B_TOT * H_TOT)
#define G_TOT 192       // partial groups = B_TOT * 32 unit-tiles
#define LO_SCALE 4096.0f
#define LO_INV   (1.0f / 4096.0f)

union H8 { f16 h[8]; uint4 v; };

// global->LDS DMA, 16 B per lane. LDS dest = wave-uniform base + lane*16.
#define GLOAD16(g, l)                                                        \
    __builtin_amdgcn_global_load_lds(                                        \
        (const __attribute__((address_space(1))) void*)(g),                  \
        (__attribute__((address_space(3))) void*)(l), 16, 0, 0)

// ---------------------------------------------------------------------------
// One-time fp32 -> (hi, lo*4096) f16 split, 8 elems/thread. n % 2048 == 0.
// ---------------------------------------------------------------------------
__global__ __launch_bounds__(256)
void split_f32(const float* __restrict__ src, f16* __restrict__ hi,
               f16* __restrict__ lo, int n)
{
    const int i = (blockIdx.x * 256 + threadIdx.x) * 8;
    if (i + 8 > n) return;
    const float4 a = *(const float4*)&src[i];
    const float4 b = *(const float4*)&src[i + 4];
    const float x[8] = {a.x, a.y, a.z, a.w, b.x, b.y, b.z, b.w};
    H8 H, L;
#pragma unroll
    for (int j = 0; j < 8; ++j) {
        const f16 h = (f16)x[j];
        H.h[j] = h;
        L.h[j] = (f16)((x[j] - (float)h) * LO_SCALE);
    }
    *(uint4*)&hi[i] = H.v;
    *(uint4*)&lo[i] = L.v;
}

// ---------------------------------------------------------------------------
// Final head reduce + argmax. Block = t (70), thread = n (256).
// ---------------------------------------------------------------------------
__global__ __launch_bounds__(256)
void head_reduce(const float* __restrict__ part,
                 const float* __restrict__ b_lin,
                 float* __restrict__ logits,
                 float* __restrict__ preds)
{
    const int t = blockIdx.x;
    const int n = threadIdx.x;

    float a0 = b_lin[t * C_TOT + 0];
    float a1 = b_lin[t * C_TOT + 1];
    float a2 = b_lin[t * C_TOT + 2];
    float a3 = b_lin[t * C_TOT + 3];

    const float* p = part + (((size_t)t * G_TOT) * N_TOT + n) * C_TOT;
    for (int g = 0; g < G_TOT; ++g) {
        const float4 v = *(const float4*)&p[(size_t)g * N_TOT * C_TOT];
        a0 += v.x; a1 += v.y; a2 += v.z; a3 += v.w;
    }

    float4 o = {a0, a1, a2, a3};
    *(float4*)&logits[((size_t)t * N_TOT + n) * C_TOT] = o;

    int arg = 0;
    float best = a0;
    if (a1 > best) { best = a1; arg = 1; }
    if (a2 > best) { best = a2; arg = 2; }
    if (a3 > best) { best = a3; arg = 3; }
    preds[(size_t)t * N_TOT + n] = (float)arg;
}

// ---------------------------------------------------------------------------
// Fused step+head: S_new = tanh(S W_res^T + X_t W_in^T); partials -> part[].
// Tile 64(M) x 32(I); grid = 768 (R18 XCD swizzle); block = 128 thr = 2
// waves, wave = 32x32 via v_mfma_f32_32x32x16_f16. 17 chunks of K=64
// (16 W_res + 1 W_in/X), 4 K-quarters each. Staging: global_load_lds into
// 2-deep LDS dbuf, 1 barrier/chunk, XOR swizzle both sides.
// ---------------------------------------------------------------------------
__global__ __launch_bounds__(128)
__attribute__((amdgpu_waves_per_eu(1, 2)))
void esn_step_fused(const f16* __restrict__ Xhi,   const f16* __restrict__ Xlo,
                    const f16* __restrict__ Whi,   const f16* __restrict__ Wlo,
                    const f16* __restrict__ Wihi,  const f16* __restrict__ Wilo,
                    const f16* __restrict__ shi_p, const f16* __restrict__ slo_p,
                    f16* __restrict__ shi_n,       f16* __restrict__ slo_n,
                    const float* __restrict__ W_lin, float* __restrict__ part,
                    int t, int first)
{
    __shared__ f16 As_hi[2][64 * 64];
    __shared__ f16 As_lo[2][64 * 64];
    __shared__ f16 Bs_hi[2][32 * 64];
    __shared__ f16 Bs_lo[2][32 * 64];

    // R18 XCD-aware bijective swizzle (768 % 8 == 0), (b,it,mt)-major.
    const int p   = blockIdx.x;
    const int l   = (p & 7) * 96 + (p >> 3);
    const int mt  = l & 3;           // batch tile 0..3  (64 rows)
    const int bi  = l >> 2;          // 0..191
    const int b   = bi >> 5;         // reservoir block 0..5
    const int it  = bi & 31;         // unit tile 0..31  (32 cols)

    const int tid  = threadIdx.x;
    const int w    = tid >> 6;       // wave = M-half (0..1)
    const int lane = tid & 63;
    const int l32  = lane & 31;
    const int hi   = lane >> 5;      // 0..1
    const int r8   = lane >> 3;      // stage stripe row 0..7
    const int sw   = ((lane & 7) ^ r8) << 3;   // swizzled source col (f16)

    // staging source pointers (per-lane, 16B-aligned). Wave w stages A rows
    // [w*32,+32) (4 stripes of 8) and B rows [w*16,+16) (2 stripes).
    const f16* Ah  = shi_p + (size_t)(b * N_TOT + mt * 64 + w * 32 + r8) * H_TOT + sw;
    const f16* Al  = slo_p + (size_t)(b * N_TOT + mt * 64 + w * 32 + r8) * H_TOT + sw;
    const f16* Bh  = Whi   + (size_t)(b * H_TOT + it * 32 + w * 16 + r8) * H_TOT + sw;
    const f16* Bl  = Wlo   + (size_t)(b * H_TOT + it * 32 + w * 16 + r8) * H_TOT + sw;
    const f16* Xh  = Xhi + ((size_t)(mt * 64 + w * 32 + r8) * T_TOT + t) * V_TOT + sw;
    const f16* Xl  = Xlo + ((size_t)(mt * 64 + w * 32 + r8) * T_TOT + t) * V_TOT + sw;
    const f16* Wih = Wihi + (size_t)(b * H_TOT + it * 32 + w * 16 + r8) * V_TOT + sw;
    const f16* Wil = Wilo + (size_t)(b * H_TOT + it * 32 + w * 16 + r8) * V_TOT + sw;

    // stage chunk k into buffer k&1 (k==16 -> input term X / W_in)
    auto STAGE = [&](int k) {
        const int bb = k & 1;
        if (k < 16) {
            const size_t off = (size_t)k * 64;
#pragma unroll
            for (int s = 0; s < 2; ++s) {
                GLOAD16(Bh + (size_t)(s * 8) * H_TOT + off, &Bs_hi[bb][(w * 16 + s * 8) * 64]);
                GLOAD16(Bl + (size_t)(s * 8) * H_TOT + off, &Bs_lo[bb][(w * 16 + s * 8) * 64]);
            }
#pragma unroll
            for (int s = 0; s < 4; ++s) {
                GLOAD16(Ah + (size_t)(s * 8) * H_TOT + off, &As_hi[bb][(w * 32 + s * 8) * 64]);
                GLOAD16(Al + (size_t)(s * 8) * H_TOT + off, &As_lo[bb][(w * 32 + s * 8) * 64]);
            }
        } else {
#pragma unroll
            for (int s = 0; s < 2; ++s) {
                GLOAD16(Wih + (size_t)(s * 8) * V_TOT, &Bs_hi[bb][(w * 16 + s * 8) * 64]);
                GLOAD16(Wil + (size_t)(s * 8) * V_TOT, &Bs_lo[bb][(w * 16 + s * 8) * 64]);
            }
#pragma unroll
            for (int s = 0; s < 4; ++s) {
                GLOAD16(Xh + (size_t)(s * 8) * T_TOT * V_TOT, &As_hi[bb][(w * 32 + s * 8) * 64]);
                GLOAD16(Xl + (size_t)(s * 8) * T_TOT * V_TOT, &As_lo[bb][(w * 32 + s * 8) * 64]);
            }
        }
    };

    floatx16 acc = (floatx16)(0.0f);
    floatx16 accl = (floatx16)(0.0f);

    // ds_read offsets (f16 elems), chunk-invariant. Operand layouts for
    // 32x32x16: A row = lane&31, k = (lane>>5)*8 + e; B(=W rows) mirrored.
    // LDS[r][g] holds source granule g^(r&7) -> read granule (2q+hi)^(lane&7).
    const int abase = (w * 32 + l32) * 64;
    const int bbase = l32 * 64;
    const int gx    = (lane & 7) << 3;
    int koff[4];
#pragma unroll
    for (int q = 0; q < 4; ++q)
        koff[q] = (((2 * q + hi) << 3) ^ gx);

    auto COMPUTE = [&](int bb) {
#pragma unroll
        for (int q = 0; q < 4; ++q) {
            const f16x8 ah = *(const f16x8*)&As_hi[bb][abase + koff[q]];
            const f16x8 al = *(const f16x8*)&As_lo[bb][abase + koff[q]];
            const f16x8 bh = *(const f16x8*)&Bs_hi[bb][bbase + koff[q]];
            const f16x8 bl = *(const f16x8*)&Bs_lo[bb][bbase + koff[q]];
            acc  = __builtin_amdgcn_mfma_f32_32x32x16_f16(ah, bh, acc, 0, 0, 0);
            accl = __builtin_amdgcn_mfma_f32_32x32x16_f16(ah, bl, accl, 0, 0, 0);
            accl = __builtin_amdgcn_mfma_f32_32x32x16_f16(al, bh, accl, 0, 0, 0);
        }
    };

    const int kc0 = first ? 16 : 0;
    STAGE(kc0);
    __syncthreads();   // vmcnt(0) drain: buffer kc0&1 ready

    for (int kc = kc0; kc <= 16; ++kc) {
        const int bb = kc & 1;
        if (kc < 16) STAGE(kc + 1);   // DMA next chunk into other buffer
        COMPUTE(bb);
        if (kc < 16) __syncthreads(); // next buffer DMA'd; this buffer free
    }

    // ---- epilogue: tanh -> split-store state; head partial -> part[] ----
    // C/D map (32x32x16): col = lane&31, row = (r&3) + 8*(r>>2) + 4*(lane>>5).
    const int nbase = mt * 64;
    const int ibase = it * 32;

    const float* wl = W_lin + (size_t)t * C_TOT * F_TOT + b * H_TOT + ibase;
    float wv[4];
#pragma unroll
    for (int c = 0; c < 4; ++c)
        wv[c] = wl[(size_t)c * F_TOT + l32];

    float sval[16];
#pragma unroll
    for (int r = 0; r < 16; ++r) {
        const int row = (r & 3) + 8 * (r >> 2) + 4 * hi;   // 0..31 in wave tile
        const int m   = w * 32 + row;                      // batch row in tile
        const float s = tanhf(acc[r] + accl[r] * LO_INV);
        sval[r] = s;
        const f16 h = (f16)s;
        const size_t oidx = (size_t)(b * N_TOT + nbase + m) * H_TOT + ibase + l32;
        shi_n[oidx] = h;
        slo_n[oidx] = (f16)((s - (float)h) * LO_SCALE);
    }

    const int g = b * 32 + it;
#pragma unroll
    for (int r = 0; r < 16; ++r) {
        float v[4];
#pragma unroll
        for (int c = 0; c < 4; ++c) {
            float x = sval[r] * wv[c];
            x += __shfl_xor(x, 1);
            x += __shfl_xor(x, 2);
            x += __shfl_xor(x, 4);
            x += __shfl_xor(x, 8);
            x += __shfl_xor(x, 16);
            v[c] = x;
        }
        if (l32 == 0) {
            const int row = (r & 3) + 8 * (r >> 2) + 4 * hi;
            const int n = nbase + w * 32 + row;
            float4 o = {v[0], v[1], v[2], v[3]};
            *(float4*)&part[(((size_t)t * G_TOT + g) * N_TOT + n) * C_TOT] = o;
        }
    }
}

extern "C" void kernel_launch(void* const* d_in, const int* in_sizes, int n_in,
                              void* d_out, int out_size, void* d_ws, size_t ws_size,
                              hipStream_t stream) {
    const float* X     = (const float*)d_in[0]; // [256,70,64]
    const float* W_res = (const float*)d_in[1]; // [6,1024,1024]
    const float* W_in  = (const float*)d_in[2]; // [6,1024,64]
    const float* W_lin = (const float*)d_in[3]; // [70,4,6144]
    const float* b_lin = (const float*)d_in[4]; // [70,4]

    float* out    = (float*)d_out;
    float* logits = out;                                  // T*N*C fp32
    float* preds  = out + (size_t)T_TOT * N_TOT * C_TOT;  // T*N   fp32

    const size_t nWres = (size_t)B_TOT * H_TOT * H_TOT;   // 6,291,456
    const size_t nWin  = (size_t)B_TOT * H_TOT * V_TOT;   //   393,216
    const size_t nX    = (size_t)N_TOT * T_TOT * V_TOT;   // 1,146,880
    const size_t nS    = (size_t)B_TOT * N_TOT * H_TOT;   // 1,572,864

    f16* p    = (f16*)d_ws;                               // f16 arena ~43.9 MB
    f16* Whi  = p;  p += nWres;
    f16* Wlo  = p;  p += nWres;
    f16* Wihi = p;  p += nWin;
    f16* Wilo = p;  p += nWin;
    f16* Xhi  = p;  p += nX;
    f16* Xlo  = p;  p += nX;
    f16* sAh  = p;  p += nS;
    f16* sAl  = p;  p += nS;
    f16* sBh  = p;  p += nS;
    f16* sBl  = p;  p += nS;
    float* part = (float*)p;                              // +55 MB (ws ~268 MB)

    // one-time pre-splits (stream-ordered before the loop)
    split_f32<<<(int)(nWres / 2048), 256, 0, stream>>>(W_res, Whi, Wlo, (int)nWres);
    split_f32<<<(int)(nWin  / 2048), 256, 0, stream>>>(W_in, Wihi, Wilo, (int)nWin);
    split_f32<<<(int)(nX    / 2048), 256, 0, stream>>>(X, Xhi, Xlo, (int)nX);

    for (int t = 0; t < T_TOT; ++t) {
        const f16 *ph, *pl;
        f16 *nh, *nl;
        if (t & 1) { ph = sBh; pl = sBl; nh = sAh; nl = sAl; }
        else       { ph = sAh; pl = sAl; nh = sBh; nl = sBl; }
        esn_step_fused<<<B_TOT * 4 * 32, 128, 0, stream>>>(
            Xhi, Xlo, Whi, Wlo, Wihi, Wilo, ph, pl, nh, nl,
            W_lin, part, t, t == 0 ? 1 : 0);
    }
    head_reduce<<<T_TOT, 256, 0, stream>>>(part, b_lin, logits, preds);
}